// Round 8
// baseline (380.989 us; speedup 1.0000x reference)
//
#include <hip/hip_runtime.h>
#include <hip/hip_bf16.h>

// GNN: 2-layer GCN (N=50000, E=800000, F=128, H=256) + mean-pool (G=512) + MLP head (257->32->4)
// Key identity: segment_sum((xW)[src]*norm) == (segment_sum(x[src]*norm)) @ W  (GCN agg is linear)
//   prep:  zero_bufs -> deg histogram -> hierarchical scan -> packed CSR scatter (int2{src,w})
//   L1: cast x->bf16; agg_gemm1: agg128 into LDS + MFMA GEMM -> h1b bf16   [fused]
//   L2: agg_gemm2_pool: agg256(h1b) into LDS + MFMA GEMM + segment-pool    [fused]
//   head: per-graph block: mean + 257->32->4 MLP
// R8/R9: widened gathers NEUTRAL -> agg at 8-XCD compulsory floor (58us, FETCH = 8 x table).
// R11/R13: sliced agg abandoned (L2-affinity real, FETCH 187->49MB, but 8x wave count
//   overhead = 142us). R14: gload_lds GEMM staging ~neutral (GEMMs not staging-bound).
// R15: fuse agg+GEMM: block = 32 nodes; phase1 = 4 waves x 8 nodes gather into LDS;
//   phase2 = 32x256 GEMM, A from LDS, B-frags direct from L2-resident weight table (no
//   B staging -> small LDS -> gather occupancy preserved). a0b/a1b buffers eliminated
//   (-77MB), 2 fewer dispatches, gather/MFMA phases of different blocks co-schedule.

#define NN 50000
#define EE 800000
#define FDIM 128
#define HDIM 256
#define GG 512
#define SCAN_NB ((NN + 255) / 256)

typedef __attribute__((ext_vector_type(8))) short short8;     // 8 bf16 = 4 VGPRs (MFMA A/B frag)
typedef __attribute__((ext_vector_type(4))) float floatx4;    // MFMA C/D frag

__device__ __forceinline__ unsigned short f2bf(float f) {   // RNE
    unsigned u = __float_as_uint(f);
    return (unsigned short)((u + 0x7FFF + ((u >> 16) & 1)) >> 16);
}
__device__ __forceinline__ float bflo(unsigned v) { return __uint_as_float(v << 16); }
__device__ __forceinline__ float bfhi(unsigned v) { return __uint_as_float(v & 0xFFFF0000u); }

// ---------------- prep kernels ----------------

__global__ __launch_bounds__(256) void zero_bufs(int* __restrict__ deg, float* __restrict__ pool) {
    int i = blockIdx.x * 256 + threadIdx.x;
    int stride = gridDim.x * 256;
    for (int k = i; k < NN; k += stride) deg[k] = 0;
    for (int k = i; k < GG * HDIM; k += stride) pool[k] = 0.f;
}

__global__ void hist_kernel(const int* __restrict__ dst, int* __restrict__ deg, int e) {
    int i = blockIdx.x * blockDim.x + threadIdx.x;
    int stride = gridDim.x * blockDim.x;
    for (; i < e; i += stride) atomicAdd(&deg[dst[i]], 1);
}

__global__ __launch_bounds__(256) void scan_part(const int* __restrict__ deg,
                                                 int* __restrict__ row_off,
                                                 int* __restrict__ blk_sums,
                                                 float* __restrict__ dinv, int n) {
    __shared__ int s[256];
    int tid = threadIdx.x;
    int i = blockIdx.x * 256 + tid;
    int v = (i < n) ? deg[i] : 0;
    if (i < n) dinv[i] = rsqrtf((float)v + 1.0f);
    s[tid] = v;
    __syncthreads();
    #pragma unroll
    for (int off = 1; off < 256; off <<= 1) {
        int t = (tid >= off) ? s[tid - off] : 0;
        __syncthreads();
        s[tid] += t;
        __syncthreads();
    }
    if (i < n) row_off[i] = s[tid] - v;
    if (tid == 255) blk_sums[blockIdx.x] = s[255];
}

__global__ __launch_bounds__(256) void scan_sums(int* __restrict__ blk_sums, int nb) {
    __shared__ int s[256];
    int tid = threadIdx.x;
    int v = (tid < nb) ? blk_sums[tid] : 0;
    s[tid] = v;
    __syncthreads();
    #pragma unroll
    for (int off = 1; off < 256; off <<= 1) {
        int t = (tid >= off) ? s[tid - off] : 0;
        __syncthreads();
        s[tid] += t;
        __syncthreads();
    }
    if (tid < nb) blk_sums[tid] = s[tid] - v;
}

__global__ __launch_bounds__(256) void scan_add(int* __restrict__ row_off,
                                                const int* __restrict__ blk_sums,
                                                int* __restrict__ fill, int n, int e) {
    int i = blockIdx.x * 256 + threadIdx.x;
    if (i < n) {
        row_off[i] += blk_sums[blockIdx.x];
        fill[i] = 0;
    }
    if (i == 0) row_off[n] = e;
}

__global__ void scatter_kernel(const int* __restrict__ src, const int* __restrict__ dst,
                               const int* __restrict__ row_off, int* __restrict__ fill,
                               const float* __restrict__ dinv,
                               int2* __restrict__ csr, int e) {
    int i = blockIdx.x * blockDim.x + threadIdx.x;
    int stride = gridDim.x * blockDim.x;
    for (; i < e; i += stride) {
        int s = src[i], d = dst[i];
        int pos = row_off[d] + atomicAdd(&fill[d], 1);
        csr[pos] = make_int2(s, __float_as_int(dinv[s] * dinv[d]));
    }
}

// merged: x fp32->bf16 cast (vectorized) + W1/W2 transpose-cast. One dispatch.
#define XCHUNKS (NN * FDIM / 4)            // 1,600,000 float4 groups
__global__ __launch_bounds__(256) void cast_all(const float* __restrict__ x,
                                                unsigned short* __restrict__ x_bf,
                                                const float* __restrict__ W1,
                                                unsigned short* __restrict__ W1t,
                                                const float* __restrict__ W2,
                                                unsigned short* __restrict__ W2t) {
    int idx = blockIdx.x * 256 + threadIdx.x;
    if (idx < XCHUNKS) {
        int i = idx * 4;
        float4 v = *(const float4*)&x[i];
        ushort4 o;
        o.x = f2bf(v.x); o.y = f2bf(v.y); o.z = f2bf(v.z); o.w = f2bf(v.w);
        *(ushort4*)&x_bf[i] = o;
        return;
    }
    int r = idx - XCHUNKS;
    if (r < FDIM * HDIM) {               // W1t[n][k] = bf16(W1[k][n]), K=128, Nc=256
        int nn = r / FDIM, k = r - nn * FDIM;
        W1t[r] = f2bf(W1[(size_t)k * HDIM + nn]);
        return;
    }
    r -= FDIM * HDIM;
    if (r < HDIM * HDIM) {               // W2t[n][k] = bf16(W2[k][n]), K=256, Nc=256
        int nn = r / HDIM, k = r - nn * HDIM;
        W2t[r] = f2bf(W2[(size_t)k * HDIM + nn]);
    }
}

// ---------------- fused agg + GEMM ----------------
// Phase 1 (gather): block owns 32 nodes; each of 4 waves aggregates 8 nodes serially
//   (same wave-split gather loops as the proven standalone agg kernels) and writes the
//   bf16 aggregate row into LDS As.
// Phase 2 (GEMM): 32x256 output; wave = 32 rows x 64 cols, acc[2][4] 16x16 tiles, K-step 32.
//   A-frags from LDS; B-frags per-lane 16B loads direct from L2-resident Wt table.
// Garbage LDS rows for node >= M only poison unstored/unpooled D rows (D row m = f(A row m)).
// NOTE: macro param must NOT be named 'w' (collides with .w member access).

#define FMA8(v, wgt) do { unsigned _u; \
    _u = (unsigned)(v).x; acc0 = fmaf(bflo(_u), (wgt), acc0); acc1 = fmaf(bfhi(_u), (wgt), acc1); \
    _u = (unsigned)(v).y; acc2 = fmaf(bflo(_u), (wgt), acc2); acc3 = fmaf(bfhi(_u), (wgt), acc3); \
    _u = (unsigned)(v).z; acc4 = fmaf(bflo(_u), (wgt), acc4); acc5 = fmaf(bfhi(_u), (wgt), acc5); \
    _u = (unsigned)(v).w; acc6 = fmaf(bflo(_u), (wgt), acc6); acc7 = fmaf(bfhi(_u), (wgt), acc7); } while (0)

// L1: in = x_bf [N][128]; out C = h1b [N][256]
__global__ __launch_bounds__(256) void agg_gemm1(const unsigned short* __restrict__ in,
                                                 const int* __restrict__ row_off,
                                                 const int2* __restrict__ csr,
                                                 const float* __restrict__ dinv,
                                                 const unsigned short* __restrict__ Bt,  // W1t [256][128]
                                                 const float* __restrict__ bias,
                                                 unsigned short* __restrict__ C, int M) {
    constexpr int K = FDIM, Nc = HDIM, LDT = 136;   // 128 + 8 pad
    __shared__ unsigned short As[32 * LDT];          // 8.7KB
    int tid = threadIdx.x;
    int lane = tid & 63, wave = tid >> 6;
    int bm = blockIdx.x * 32;

    {   // ---- phase 1: aggregate 8 nodes per wave into As ----
        int sub = lane >> 4;          // edge slot 0..3
        int fl  = lane & 15;          // 16B chunk within 256B row
        for (int r8 = 0; r8 < 8; ++r8) {
            int nodeRow = wave * 8 + r8;
            int node = bm + nodeRow;
            if (node >= M) break;                    // wave-uniform
            float di = dinv[node];
            float w0 = (sub == 0) ? di * di : 0.f;
            float acc0, acc1, acc2, acc3, acc4, acc5, acc6, acc7;
            {
                int4 sv = *(const int4*)&in[(size_t)node * 128 + fl * 8];
                unsigned _u;
                _u = (unsigned)sv.x; acc0 = bflo(_u) * w0; acc1 = bfhi(_u) * w0;
                _u = (unsigned)sv.y; acc2 = bflo(_u) * w0; acc3 = bfhi(_u) * w0;
                _u = (unsigned)sv.z; acc4 = bflo(_u) * w0; acc5 = bfhi(_u) * w0;
                _u = (unsigned)sv.w; acc6 = bflo(_u) * w0; acc7 = bfhi(_u) * w0;
            }
            int beg = __builtin_amdgcn_readfirstlane(row_off[node]);
            int end = __builtin_amdgcn_readfirstlane(row_off[node + 1]);
            if (end > beg) {
                int last = end - 1;
                int base = beg;
                int i0 = base + sub, i1 = base + 4 + sub;
                int2 c0 = csr[i0 < end ? i0 : last];
                int2 c1 = csr[i1 < end ? i1 : last];
                int nIter = (end - beg + 7) >> 3;
                for (int it = 0; it < nIter; ++it) {
                    int4 g0 = *(const int4*)&in[(size_t)c0.x * 128 + fl * 8];
                    int4 g1 = *(const int4*)&in[(size_t)c1.x * 128 + fl * 8];
                    float we0 = (base + sub < end) ? __int_as_float(c0.y) : 0.f;
                    float we1 = (base + 4 + sub < end) ? __int_as_float(c1.y) : 0.f;
                    int nb = base + 8;
                    int j0 = nb + sub, j1 = nb + 4 + sub;
                    int2 n0 = csr[j0 < end ? j0 : last];
                    int2 n1 = csr[j1 < end ? j1 : last];
                    FMA8(g0, we0); FMA8(g1, we1);
                    c0 = n0; c1 = n1; base = nb;
                }
            }
            acc0 += __shfl_xor(acc0, 16); acc1 += __shfl_xor(acc1, 16);
            acc2 += __shfl_xor(acc2, 16); acc3 += __shfl_xor(acc3, 16);
            acc4 += __shfl_xor(acc4, 16); acc5 += __shfl_xor(acc5, 16);
            acc6 += __shfl_xor(acc6, 16); acc7 += __shfl_xor(acc7, 16);
            acc0 += __shfl_xor(acc0, 32); acc1 += __shfl_xor(acc1, 32);
            acc2 += __shfl_xor(acc2, 32); acc3 += __shfl_xor(acc3, 32);
            acc4 += __shfl_xor(acc4, 32); acc5 += __shfl_xor(acc5, 32);
            acc6 += __shfl_xor(acc6, 32); acc7 += __shfl_xor(acc7, 32);
            if (sub == 0) {
                int4 o;
                o.x = (int)((unsigned)f2bf(acc0) | ((unsigned)f2bf(acc1) << 16));
                o.y = (int)((unsigned)f2bf(acc2) | ((unsigned)f2bf(acc3) << 16));
                o.z = (int)((unsigned)f2bf(acc4) | ((unsigned)f2bf(acc5) << 16));
                o.w = (int)((unsigned)f2bf(acc6) | ((unsigned)f2bf(acc7) << 16));
                *(int4*)&As[nodeRow * LDT + fl * 8] = o;
            }
        }
    }
    __syncthreads();

    // ---- phase 2: GEMM 32x256, wave = 32 rows x 64 cols ----
    int l15 = lane & 15, quad = lane >> 4;
    int wn = wave * 64;
    floatx4 zero = {0.f, 0.f, 0.f, 0.f};
    floatx4 acc[2][4];
    #pragma unroll
    for (int s = 0; s < 2; ++s)
        #pragma unroll
        for (int t = 0; t < 4; ++t) acc[s][t] = zero;
    #pragma unroll
    for (int k0 = 0; k0 < K; k0 += 32) {
        short8 af[2], bf[4];
        #pragma unroll
        for (int s = 0; s < 2; ++s)
            af[s] = *(const short8*)&As[(s * 16 + l15) * LDT + k0 + quad * 8];
        #pragma unroll
        for (int t = 0; t < 4; ++t)
            bf[t] = *(const short8*)&Bt[(size_t)(wn + t * 16 + l15) * K + k0 + quad * 8];
        #pragma unroll
        for (int s = 0; s < 2; ++s)
            #pragma unroll
            for (int t = 0; t < 4; ++t)
                acc[s][t] = __builtin_amdgcn_mfma_f32_16x16x32_bf16(af[s], bf[t], acc[s][t], 0, 0, 0);
    }
    #pragma unroll
    for (int s = 0; s < 2; ++s) {
        int row0 = bm + s * 16 + quad * 4;
        #pragma unroll
        for (int t = 0; t < 4; ++t) {
            int col = wn + t * 16 + l15;
            float bb = bias[col];
            #pragma unroll
            for (int r = 0; r < 4; ++r) {
                int row = row0 + r;
                if (row < M)
                    C[(size_t)row * Nc + col] = f2bf(fmaxf(acc[s][t][r] + bb, 0.f));
            }
        }
    }
}

// L2: in = h1b [N][256]; relu(agg @ W2 + b2) segment-pooled into pool[G][256]
__global__ __launch_bounds__(256) void agg_gemm2_pool(const unsigned short* __restrict__ in,
                                                      const int* __restrict__ row_off,
                                                      const int2* __restrict__ csr,
                                                      const float* __restrict__ dinv,
                                                      const unsigned short* __restrict__ Bt, // W2t [256][256]
                                                      const float* __restrict__ bias,
                                                      const int* __restrict__ batch,
                                                      float* __restrict__ pool, int M) {
    constexpr int K = HDIM, Nc = HDIM, LDT = 264;   // 256 + 8 pad
    __shared__ unsigned short As[32 * LDT];          // 16.9KB
    int tid = threadIdx.x;
    int lane = tid & 63, wave = tid >> 6;
    int bm = blockIdx.x * 32;

    {   // ---- phase 1: aggregate 8 nodes per wave into As ----
        int sub = lane >> 5;          // edge slot 0..1
        int fl  = lane & 31;          // 16B chunk within 512B row
        for (int r8 = 0; r8 < 8; ++r8) {
            int nodeRow = wave * 8 + r8;
            int node = bm + nodeRow;
            if (node >= M) break;                    // wave-uniform
            float di = dinv[node];
            float w0 = (sub == 0) ? di * di : 0.f;
            float acc0, acc1, acc2, acc3, acc4, acc5, acc6, acc7;
            {
                int4 sv = *(const int4*)&in[(size_t)node * 256 + fl * 8];
                unsigned _u;
                _u = (unsigned)sv.x; acc0 = bflo(_u) * w0; acc1 = bfhi(_u) * w0;
                _u = (unsigned)sv.y; acc2 = bflo(_u) * w0; acc3 = bfhi(_u) * w0;
                _u = (unsigned)sv.z; acc4 = bflo(_u) * w0; acc5 = bfhi(_u) * w0;
                _u = (unsigned)sv.w; acc6 = bflo(_u) * w0; acc7 = bfhi(_u) * w0;
            }
            int beg = __builtin_amdgcn_readfirstlane(row_off[node]);
            int end = __builtin_amdgcn_readfirstlane(row_off[node + 1]);
            if (end > beg) {
                int last = end - 1;
                int base = beg;
                int i0 = base + 0 + sub, i1 = base + 2 + sub;
                int i2 = base + 4 + sub, i3 = base + 6 + sub;
                int2 c0 = csr[i0 < end ? i0 : last];
                int2 c1 = csr[i1 < end ? i1 : last];
                int2 c2 = csr[i2 < end ? i2 : last];
                int2 c3 = csr[i3 < end ? i3 : last];
                int nIter = (end - beg + 7) >> 3;
                for (int it = 0; it < nIter; ++it) {
                    int4 g0 = *(const int4*)&in[(size_t)c0.x * 256 + fl * 8];
                    int4 g1 = *(const int4*)&in[(size_t)c1.x * 256 + fl * 8];
                    int4 g2 = *(const int4*)&in[(size_t)c2.x * 256 + fl * 8];
                    int4 g3 = *(const int4*)&in[(size_t)c3.x * 256 + fl * 8];
                    float we0 = (base + 0 + sub < end) ? __int_as_float(c0.y) : 0.f;
                    float we1 = (base + 2 + sub < end) ? __int_as_float(c1.y) : 0.f;
                    float we2 = (base + 4 + sub < end) ? __int_as_float(c2.y) : 0.f;
                    float we3 = (base + 6 + sub < end) ? __int_as_float(c3.y) : 0.f;
                    int nb = base + 8;
                    int j0 = nb + 0 + sub, j1 = nb + 2 + sub;
                    int j2 = nb + 4 + sub, j3 = nb + 6 + sub;
                    int2 n0 = csr[j0 < end ? j0 : last];
                    int2 n1 = csr[j1 < end ? j1 : last];
                    int2 n2 = csr[j2 < end ? j2 : last];
                    int2 n3 = csr[j3 < end ? j3 : last];
                    FMA8(g0, we0); FMA8(g1, we1); FMA8(g2, we2); FMA8(g3, we3);
                    c0 = n0; c1 = n1; c2 = n2; c3 = n3; base = nb;
                }
            }
            acc0 += __shfl_xor(acc0, 32); acc1 += __shfl_xor(acc1, 32);
            acc2 += __shfl_xor(acc2, 32); acc3 += __shfl_xor(acc3, 32);
            acc4 += __shfl_xor(acc4, 32); acc5 += __shfl_xor(acc5, 32);
            acc6 += __shfl_xor(acc6, 32); acc7 += __shfl_xor(acc7, 32);
            if (sub == 0) {
                int4 o;
                o.x = (int)((unsigned)f2bf(acc0) | ((unsigned)f2bf(acc1) << 16));
                o.y = (int)((unsigned)f2bf(acc2) | ((unsigned)f2bf(acc3) << 16));
                o.z = (int)((unsigned)f2bf(acc4) | ((unsigned)f2bf(acc5) << 16));
                o.w = (int)((unsigned)f2bf(acc6) | ((unsigned)f2bf(acc7) << 16));
                *(int4*)&As[nodeRow * LDT + fl * 8] = o;
            }
        }
    }
    __syncthreads();

    // ---- phase 2: GEMM 32x256 + segment-pool ----
    int l15 = lane & 15, quad = lane >> 4;
    int wn = wave * 64;
    floatx4 zero = {0.f, 0.f, 0.f, 0.f};
    floatx4 acc[2][4];
    #pragma unroll
    for (int s = 0; s < 2; ++s)
        #pragma unroll
        for (int t = 0; t < 4; ++t) acc[s][t] = zero;
    #pragma unroll
    for (int k0 = 0; k0 < K; k0 += 32) {
        short8 af[2], bf[4];
        #pragma unroll
        for (int s = 0; s < 2; ++s)
            af[s] = *(const short8*)&As[(s * 16 + l15) * LDT + k0 + quad * 8];
        #pragma unroll
        for (int t = 0; t < 4; ++t)
            bf[t] = *(const short8*)&Bt[(size_t)(wn + t * 16 + l15) * K + k0 + quad * 8];
        #pragma unroll
        for (int s = 0; s < 2; ++s)
            #pragma unroll
            for (int t = 0; t < 4; ++t)
                acc[s][t] = __builtin_amdgcn_mfma_f32_16x16x32_bf16(af[s], bf[t], acc[s][t], 0, 0, 0);
    }
    #pragma unroll
    for (int s = 0; s < 2; ++s) {
        int row0 = bm + s * 16 + quad * 4;
        if (row0 >= M) continue;
        bool full = (row0 + 3 < M);
        int gA = batch[row0];
        int gB = full ? batch[row0 + 3] : gA;
        bool same = full && (gA == gB);
        #pragma unroll
        for (int t = 0; t < 4; ++t) {
            int col = wn + t * 16 + l15;
            float bb = bias[col];
            if (same) {
                float v = fmaxf(acc[s][t][0] + bb, 0.f) + fmaxf(acc[s][t][1] + bb, 0.f)
                        + fmaxf(acc[s][t][2] + bb, 0.f) + fmaxf(acc[s][t][3] + bb, 0.f);
                atomicAdd(&pool[(size_t)gA * Nc + col], v);
            } else {
                #pragma unroll
                for (int r = 0; r < 4; ++r) {
                    int row = row0 + r;
                    if (row < M) {
                        float v = fmaxf(acc[s][t][r] + bb, 0.f);
                        atomicAdd(&pool[(size_t)batch[row] * Nc + col], v);
                    }
                }
            }
        }
    }
}

// ---------------- head: one block per graph, reads pooled sums ----------------

__device__ __forceinline__ int lower_bound_i(const int* __restrict__ a, int n, int v) {
    int lo = 0, hi = n;
    while (lo < hi) {
        int mid = (lo + hi) >> 1;
        if (a[mid] < v) lo = mid + 1; else hi = mid;
    }
    return lo;
}

__global__ __launch_bounds__(256) void head_kernel(const float* __restrict__ pool,
                                                   const int* __restrict__ batch,
                                                   const float* __restrict__ num_atoms,
                                                   const float* __restrict__ W3, const float* __restrict__ b3,
                                                   const float* __restrict__ W4, const float* __restrict__ b4,
                                                   float* __restrict__ out, int n) {
    int g = blockIdx.x;
    int tid = threadIdx.x;
    __shared__ int s_lo, s_hi;
    if (tid == 0) {
        s_lo = lower_bound_i(batch, n, g);
        s_hi = lower_bound_i(batch, n, g + 1);
    }
    __syncthreads();
    float cnt = (float)(s_hi - s_lo);

    __shared__ float zin[HDIM + 1];
    __shared__ float z[32];
    zin[tid] = pool[(size_t)g * HDIM + tid] / fmaxf(cnt, 1.0f);
    if (tid == 0) zin[HDIM] = num_atoms[g];
    __syncthreads();
    if (tid < 32) {
        float a = b3[tid];
        for (int k = 0; k < HDIM + 1; ++k) a = fmaf(zin[k], W3[k * 32 + tid], a);
        z[tid] = fmaxf(a, 0.f);
    }
    __syncthreads();
    if (tid < 4) {
        float a = b4[tid];
        #pragma unroll
        for (int k = 0; k < 32; ++k) a = fmaf(z[k], W4[k * 4 + tid], a);
        out[g * 4 + tid] = a;
    }
}

// ---------------- launch ----------------

extern "C" void kernel_launch(void* const* d_in, const int* in_sizes, int n_in,
                              void* d_out, int out_size, void* d_ws, size_t ws_size,
                              hipStream_t stream) {
    const float* x         = (const float*)d_in[0];
    const int*   edge_idx  = (const int*)d_in[1];
    const int*   batch     = (const int*)d_in[2];
    const float* num_atoms = (const float*)d_in[3];
    const float* W1 = (const float*)d_in[4];
    const float* b1 = (const float*)d_in[5];
    const float* W2 = (const float*)d_in[6];
    const float* b2 = (const float*)d_in[7];
    const float* W3 = (const float*)d_in[8];
    const float* b3 = (const float*)d_in[9];
    const float* W4 = (const float*)d_in[10];
    const float* b4 = (const float*)d_in[11];
    float* out = (float*)d_out;

    const int n = NN, e = EE;
    const int* e_src = edge_idx;
    const int* e_dst = edge_idx + e;

    // workspace (256B aligned):
    //   x_bf (12.8MB): [N,128] bf16, live through agg_gemm1.
    //   h1b  (25.6MB): [N,256] bf16, agg_gemm1 out -> agg_gemm2_pool gathers.
    //   pool (512KB):  [G,256] fp32 pooled sums -> head.
    char* ws = (char*)d_ws;
    size_t off = 0;
    auto carve = [&](size_t bytes) -> void* {
        void* p = ws + off;
        off = (off + bytes + 255) & ~(size_t)255;
        return p;
    };
    int*   deg_i    = (int*)carve((size_t)n * 4);
    int*   row_off  = (int*)carve((size_t)(n + 1) * 4);
    int*   fill     = (int*)carve((size_t)n * 4);
    int*   blk_sums = (int*)carve((size_t)256 * 4);
    float* dinv     = (float*)carve((size_t)n * 4);
    unsigned short* W1t = (unsigned short*)carve((size_t)FDIM * HDIM * 2);
    unsigned short* W2t = (unsigned short*)carve((size_t)HDIM * HDIM * 2);
    int2*  csr      = (int2*)carve((size_t)e * 8);
    unsigned short* x_bf = (unsigned short*)carve((size_t)n * FDIM * 2);
    unsigned short* h1b  = (unsigned short*)carve((size_t)n * HDIM * 2);
    float* pool     = (float*)carve((size_t)GG * HDIM * 4);
    (void)ws_size; (void)n_in; (void)in_sizes; (void)out_size;

    zero_bufs<<<256, 256, 0, stream>>>(deg_i, pool);
    hist_kernel<<<1024, 256, 0, stream>>>(e_dst, deg_i, e);
    scan_part<<<SCAN_NB, 256, 0, stream>>>(deg_i, row_off, blk_sums, dinv, n);
    scan_sums<<<1, 256, 0, stream>>>(blk_sums, SCAN_NB);
    scan_add<<<SCAN_NB, 256, 0, stream>>>(row_off, blk_sums, fill, n, e);
    scatter_kernel<<<1024, 256, 0, stream>>>(e_src, e_dst, row_off, fill, dinv, csr, e);

    // cast x + transpose-cast W1,W2 in one dispatch
    cast_all<<<(XCHUNKS + FDIM * HDIM + HDIM * HDIM + 255) / 256, 256, 0, stream>>>(
        x, x_bf, W1, W1t, W2, W2t);

    int fused_grid = (n + 31) / 32;
    // L1: h1b = relu(agg128(x_bf) @ W1 + b1)   [fused gather+GEMM]
    agg_gemm1<<<fused_grid, 256, 0, stream>>>(x_bf, row_off, csr, dinv, W1t, b1, h1b, n);
    // L2: pool += segsum(relu(agg256(h1b) @ W2 + b2))   [fused gather+GEMM+pool]
    agg_gemm2_pool<<<fused_grid, 256, 0, stream>>>(h1b, row_off, csr, dinv, W2t, b2, batch, pool, n);
    // head
    head_kernel<<<GG, 256, 0, stream>>>(pool, batch, num_atoms, W3, b3, W4, b4, out, n);
}

// Round 9
// 322.223 us; speedup vs baseline: 1.1824x; 1.1824x over previous
//
#include <hip/hip_runtime.h>
#include <hip/hip_bf16.h>

// GNN: 2-layer GCN (N=50000, E=800000, F=128, H=256) + mean-pool (G=512) + MLP head (257->32->4)
// Key identity: segment_sum((xW)[src]*norm) == (segment_sum(x[src]*norm)) @ W  (GCN agg is linear)
//   prep:  cast_all (x->bf16, W transpose, zero deg/pool) -> hist(+epos) -> scan -> scatter
//   L1: agg128 -> a0; h1 = relu(a0 @ W1 + b1) -> bf16   [MFMA, 128x256 tile]
//   L2: agg256(h1) -> a1; gemm2_pool: relu(a1 @ W2 + b2) pooled into pool[G,256]
//   head: per-graph block: mean + 257->32->4 MLP
// R8/R9: widened gathers NEUTRAL -> agg at 8-XCD compulsory floor (58us, FETCH = 8 x table).
// R11/R13: sliced agg abandoned (L2-affinity real but 8x wave-count overhead).
// R14: gload_lds GEMM staging ~neutral. R15: agg+GEMM fusion REFUTED (118us): block-local
//   barrier cut gather TLP 8x (6250 waves vs 50000) -> MLP starvation. Reverted.
// R16: prep trim: (a) hist returns per-edge ordinal epos[] -> scatter has NO atomics;
//   (b) zero_bufs folded into cast_all; fill[] eliminated. 12 -> 11 dispatches.

#define NN 50000
#define EE 800000
#define FDIM 128
#define HDIM 256
#define GG 512
#define SCAN_NB ((NN + 255) / 256)

typedef __attribute__((ext_vector_type(8))) short short8;     // 8 bf16 = 4 VGPRs (MFMA A/B frag)
typedef __attribute__((ext_vector_type(4))) float floatx4;    // MFMA C/D frag

__device__ __forceinline__ unsigned short f2bf(float f) {   // RNE
    unsigned u = __float_as_uint(f);
    return (unsigned short)((u + 0x7FFF + ((u >> 16) & 1)) >> 16);
}
__device__ __forceinline__ float bflo(unsigned v) { return __uint_as_float(v << 16); }
__device__ __forceinline__ float bfhi(unsigned v) { return __uint_as_float(v & 0xFFFF0000u); }

// async global->LDS, 16B per lane. lds ptr must be wave-uniform (HW adds lane*16).
__device__ __forceinline__ void gload16(const void* g, void* l) {
    __builtin_amdgcn_global_load_lds((const __attribute__((address_space(1))) void*)g,
                                     (__attribute__((address_space(3))) void*)l, 16, 0, 0);
}

// ---------------- prep kernels ----------------

// hist + per-edge ordinal: epos[i] = old count of dst[i]. Scatter then needs no atomics.
__global__ void hist_kernel(const int* __restrict__ dst, int* __restrict__ deg,
                            int* __restrict__ epos, int e) {
    int i = blockIdx.x * blockDim.x + threadIdx.x;
    int stride = gridDim.x * blockDim.x;
    for (; i < e; i += stride) epos[i] = atomicAdd(&deg[dst[i]], 1);
}

__global__ __launch_bounds__(256) void scan_part(const int* __restrict__ deg,
                                                 int* __restrict__ row_off,
                                                 int* __restrict__ blk_sums,
                                                 float* __restrict__ dinv, int n) {
    __shared__ int s[256];
    int tid = threadIdx.x;
    int i = blockIdx.x * 256 + tid;
    int v = (i < n) ? deg[i] : 0;
    if (i < n) dinv[i] = rsqrtf((float)v + 1.0f);
    s[tid] = v;
    __syncthreads();
    #pragma unroll
    for (int off = 1; off < 256; off <<= 1) {
        int t = (tid >= off) ? s[tid - off] : 0;
        __syncthreads();
        s[tid] += t;
        __syncthreads();
    }
    if (i < n) row_off[i] = s[tid] - v;
    if (tid == 255) blk_sums[blockIdx.x] = s[255];
}

__global__ __launch_bounds__(256) void scan_sums(int* __restrict__ blk_sums, int nb) {
    __shared__ int s[256];
    int tid = threadIdx.x;
    int v = (tid < nb) ? blk_sums[tid] : 0;
    s[tid] = v;
    __syncthreads();
    #pragma unroll
    for (int off = 1; off < 256; off <<= 1) {
        int t = (tid >= off) ? s[tid - off] : 0;
        __syncthreads();
        s[tid] += t;
        __syncthreads();
    }
    if (tid < nb) blk_sums[tid] = s[tid] - v;
}

__global__ __launch_bounds__(256) void scan_add(int* __restrict__ row_off,
                                                const int* __restrict__ blk_sums,
                                                int n, int e) {
    int i = blockIdx.x * 256 + threadIdx.x;
    if (i < n) row_off[i] += blk_sums[blockIdx.x];
    if (i == 0) row_off[n] = e;
}

// atomic-free scatter: position = row_off[dst] + epos (ordinal captured in hist)
__global__ void scatter_kernel(const int* __restrict__ src, const int* __restrict__ dst,
                               const int* __restrict__ row_off, const int* __restrict__ epos,
                               const float* __restrict__ dinv,
                               int2* __restrict__ csr, int e) {
    int i = blockIdx.x * blockDim.x + threadIdx.x;
    int stride = gridDim.x * blockDim.x;
    for (; i < e; i += stride) {
        int s = src[i], d = dst[i];
        int pos = row_off[d] + epos[i];
        csr[pos] = make_int2(s, __float_as_int(dinv[s] * dinv[d]));
    }
}

// merged: x fp32->bf16 cast + W1/W2 transpose-cast + zero deg/pool. One dispatch.
#define XCHUNKS (NN * FDIM / 4)            // 1,600,000 float4 groups
#define CAST_TOTAL (XCHUNKS + FDIM * HDIM + HDIM * HDIM + NN / 4 + GG * HDIM / 4)
__global__ __launch_bounds__(256) void cast_all(const float* __restrict__ x,
                                                unsigned short* __restrict__ x_bf,
                                                const float* __restrict__ W1,
                                                unsigned short* __restrict__ W1t,
                                                const float* __restrict__ W2,
                                                unsigned short* __restrict__ W2t,
                                                int* __restrict__ deg,
                                                float* __restrict__ pool) {
    int idx = blockIdx.x * 256 + threadIdx.x;
    if (idx < XCHUNKS) {
        int i = idx * 4;
        float4 v = *(const float4*)&x[i];
        ushort4 o;
        o.x = f2bf(v.x); o.y = f2bf(v.y); o.z = f2bf(v.z); o.w = f2bf(v.w);
        *(ushort4*)&x_bf[i] = o;
        return;
    }
    int r = idx - XCHUNKS;
    if (r < FDIM * HDIM) {               // W1t[n][k] = bf16(W1[k][n]), K=128, Nc=256
        int nn = r / FDIM, k = r - nn * FDIM;
        W1t[r] = f2bf(W1[(size_t)k * HDIM + nn]);
        return;
    }
    r -= FDIM * HDIM;
    if (r < HDIM * HDIM) {               // W2t[n][k] = bf16(W2[k][n]), K=256, Nc=256
        int nn = r / HDIM, k = r - nn * HDIM;
        W2t[r] = f2bf(W2[(size_t)k * HDIM + nn]);
        return;
    }
    r -= HDIM * HDIM;
    if (r < NN / 4) {                    // zero deg (50000 % 4 == 0)
        int4 z = {0, 0, 0, 0};
        *(int4*)&deg[r * 4] = z;
        return;
    }
    r -= NN / 4;
    if (r < GG * HDIM / 4) {             // zero pool
        float4 z = {0.f, 0.f, 0.f, 0.f};
        *(float4*)&pool[r * 4] = z;
    }
}

// ---------------- GCN aggregation (bf16 payload, fp32 accumulate, bf16 out) ----------------
// out[d] = sum_e in[src_e]*w_e + in[d]*dinv[d]^2
// wave-per-node, dwordx4 gathers (16B/lane). Wave split across edges.
// At the 8-XCD compulsory-traffic floor (FETCH = 8 x table): final form.
// NOTE: macro param must NOT be named 'w' (collides with .w member access).

#define FMA8(v, wgt) do { unsigned _u; \
    _u = (unsigned)(v).x; acc0 = fmaf(bflo(_u), (wgt), acc0); acc1 = fmaf(bfhi(_u), (wgt), acc1); \
    _u = (unsigned)(v).y; acc2 = fmaf(bflo(_u), (wgt), acc2); acc3 = fmaf(bfhi(_u), (wgt), acc3); \
    _u = (unsigned)(v).z; acc4 = fmaf(bflo(_u), (wgt), acc4); acc5 = fmaf(bfhi(_u), (wgt), acc5); \
    _u = (unsigned)(v).w; acc6 = fmaf(bflo(_u), (wgt), acc6); acc7 = fmaf(bfhi(_u), (wgt), acc7); } while (0)

__global__ __launch_bounds__(256) void gcn_agg256_bf16(const unsigned short* __restrict__ in,
                                                       const int* __restrict__ row_off,
                                                       const int2* __restrict__ csr,
                                                       const float* __restrict__ dinv,
                                                       unsigned short* __restrict__ out, int n) {
    int wave = threadIdx.x >> 6;
    int lane = threadIdx.x & 63;
    int node = blockIdx.x * 4 + wave;
    if (node >= n) return;
    int sub = lane >> 5;          // edge slot 0..1
    int fl  = lane & 31;          // 16B feature chunk within row
    float di = dinv[node];
    float w0 = (sub == 0) ? di * di : 0.f;

    float acc0, acc1, acc2, acc3, acc4, acc5, acc6, acc7;
    {   // self term (both halves read same line; only sub==0 weighted)
        int4 sv = *(const int4*)&in[(size_t)node * 256 + fl * 8];
        unsigned _u;
        _u = (unsigned)sv.x; acc0 = bflo(_u) * w0; acc1 = bfhi(_u) * w0;
        _u = (unsigned)sv.y; acc2 = bflo(_u) * w0; acc3 = bfhi(_u) * w0;
        _u = (unsigned)sv.z; acc4 = bflo(_u) * w0; acc5 = bfhi(_u) * w0;
        _u = (unsigned)sv.w; acc6 = bflo(_u) * w0; acc7 = bfhi(_u) * w0;
    }

    int beg = __builtin_amdgcn_readfirstlane(row_off[node]);
    int end = __builtin_amdgcn_readfirstlane(row_off[node + 1]);
    int cnt = end - beg;
    if (cnt > 0) {
        int nIter = (cnt + 7) >> 3;                    // 8 edges / iter
        int base = beg;
        int last = end - 1;
        int i0 = base + 0 + sub, i1 = base + 2 + sub, i2 = base + 4 + sub, i3 = base + 6 + sub;
        int2 c0 = csr[i0 < end ? i0 : last];
        int2 c1 = csr[i1 < end ? i1 : last];
        int2 c2 = csr[i2 < end ? i2 : last];
        int2 c3 = csr[i3 < end ? i3 : last];
        for (int it = 0; it < nIter; ++it) {
            int4 g0 = *(const int4*)&in[(size_t)c0.x * 256 + fl * 8];
            int4 g1 = *(const int4*)&in[(size_t)c1.x * 256 + fl * 8];
            int4 g2 = *(const int4*)&in[(size_t)c2.x * 256 + fl * 8];
            int4 g3 = *(const int4*)&in[(size_t)c3.x * 256 + fl * 8];
            float we0 = (base + 0 + sub < end) ? __int_as_float(c0.y) : 0.f;
            float we1 = (base + 2 + sub < end) ? __int_as_float(c1.y) : 0.f;
            float we2 = (base + 4 + sub < end) ? __int_as_float(c2.y) : 0.f;
            float we3 = (base + 6 + sub < end) ? __int_as_float(c3.y) : 0.f;
            int nb = base + 8;
            int j0 = nb + 0 + sub, j1 = nb + 2 + sub, j2 = nb + 4 + sub, j3 = nb + 6 + sub;
            int2 n0 = csr[j0 < end ? j0 : last];
            int2 n1 = csr[j1 < end ? j1 : last];
            int2 n2 = csr[j2 < end ? j2 : last];
            int2 n3 = csr[j3 < end ? j3 : last];
            FMA8(g0, we0); FMA8(g1, we1); FMA8(g2, we2); FMA8(g3, we3);
            c0 = n0; c1 = n1; c2 = n2; c3 = n3; base = nb;
        }
    }
    // combine edge-slot halves
    acc0 += __shfl_xor(acc0, 32); acc1 += __shfl_xor(acc1, 32);
    acc2 += __shfl_xor(acc2, 32); acc3 += __shfl_xor(acc3, 32);
    acc4 += __shfl_xor(acc4, 32); acc5 += __shfl_xor(acc5, 32);
    acc6 += __shfl_xor(acc6, 32); acc7 += __shfl_xor(acc7, 32);
    if (sub == 0) {
        int4 o;
        o.x = (int)((unsigned)f2bf(acc0) | ((unsigned)f2bf(acc1) << 16));
        o.y = (int)((unsigned)f2bf(acc2) | ((unsigned)f2bf(acc3) << 16));
        o.z = (int)((unsigned)f2bf(acc4) | ((unsigned)f2bf(acc5) << 16));
        o.w = (int)((unsigned)f2bf(acc6) | ((unsigned)f2bf(acc7) << 16));
        *(int4*)&out[(size_t)node * 256 + fl * 8] = o;
    }
}

__global__ __launch_bounds__(256) void gcn_agg128_bf16(const unsigned short* __restrict__ in,
                                                       const int* __restrict__ row_off,
                                                       const int2* __restrict__ csr,
                                                       const float* __restrict__ dinv,
                                                       unsigned short* __restrict__ out, int n) {
    int wave = threadIdx.x >> 6;
    int lane = threadIdx.x & 63;
    int node = blockIdx.x * 4 + wave;
    if (node >= n) return;
    int sub = lane >> 4;          // edge slot 0..3
    int fl  = lane & 15;          // 16B feature chunk within row
    float di = dinv[node];
    float w0 = (sub == 0) ? di * di : 0.f;

    float acc0, acc1, acc2, acc3, acc4, acc5, acc6, acc7;
    {   // self term
        int4 sv = *(const int4*)&in[(size_t)node * 128 + fl * 8];
        unsigned _u;
        _u = (unsigned)sv.x; acc0 = bflo(_u) * w0; acc1 = bfhi(_u) * w0;
        _u = (unsigned)sv.y; acc2 = bflo(_u) * w0; acc3 = bfhi(_u) * w0;
        _u = (unsigned)sv.z; acc4 = bflo(_u) * w0; acc5 = bfhi(_u) * w0;
        _u = (unsigned)sv.w; acc6 = bflo(_u) * w0; acc7 = bfhi(_u) * w0;
    }

    int beg = __builtin_amdgcn_readfirstlane(row_off[node]);
    int end = __builtin_amdgcn_readfirstlane(row_off[node + 1]);
    int cnt = end - beg;
    if (cnt > 0) {
        int nIter = (cnt + 7) >> 3;                    // 8 edges / iter (2 gathers)
        int base = beg;
        int last = end - 1;
        int i0 = base + sub, i1 = base + 4 + sub;
        int2 c0 = csr[i0 < end ? i0 : last];
        int2 c1 = csr[i1 < end ? i1 : last];
        for (int it = 0; it < nIter; ++it) {
            int4 g0 = *(const int4*)&in[(size_t)c0.x * 128 + fl * 8];
            int4 g1 = *(const int4*)&in[(size_t)c1.x * 128 + fl * 8];
            float we0 = (base + sub < end) ? __int_as_float(c0.y) : 0.f;
            float we1 = (base + 4 + sub < end) ? __int_as_float(c1.y) : 0.f;
            int nb = base + 8;
            int j0 = nb + sub, j1 = nb + 4 + sub;
            int2 n0 = csr[j0 < end ? j0 : last];
            int2 n1 = csr[j1 < end ? j1 : last];
            FMA8(g0, we0); FMA8(g1, we1);
            c0 = n0; c1 = n1; base = nb;
        }
    }
    // combine 4 edge-slots
    acc0 += __shfl_xor(acc0, 16); acc1 += __shfl_xor(acc1, 16);
    acc2 += __shfl_xor(acc2, 16); acc3 += __shfl_xor(acc3, 16);
    acc4 += __shfl_xor(acc4, 16); acc5 += __shfl_xor(acc5, 16);
    acc6 += __shfl_xor(acc6, 16); acc7 += __shfl_xor(acc7, 16);
    acc0 += __shfl_xor(acc0, 32); acc1 += __shfl_xor(acc1, 32);
    acc2 += __shfl_xor(acc2, 32); acc3 += __shfl_xor(acc3, 32);
    acc4 += __shfl_xor(acc4, 32); acc5 += __shfl_xor(acc5, 32);
    acc6 += __shfl_xor(acc6, 32); acc7 += __shfl_xor(acc7, 32);
    if (sub == 0) {
        int4 o;
        o.x = (int)((unsigned)f2bf(acc0) | ((unsigned)f2bf(acc1) << 16));
        o.y = (int)((unsigned)f2bf(acc2) | ((unsigned)f2bf(acc3) << 16));
        o.z = (int)((unsigned)f2bf(acc4) | ((unsigned)f2bf(acc5) << 16));
        o.w = (int)((unsigned)f2bf(acc6) | ((unsigned)f2bf(acc7) << 16));
        *(int4*)&out[(size_t)node * 128 + fl * 8] = o;
    }
}

// ---------------- bf16 MFMA GEMM, 128x256 single-column tile, 8 waves (2x4) ----------------
// A bf16 row-major [M][K], Bt bf16 [256][K] pre-transposed. Wave = 64x64 via 4x4 16x16x32.
// Staging via global_load_lds width=16 into LINEAR LDS (LDT=32). No staging guards:
// over-reads past M stay inside workspace. Verified layouts (learn_hip m89/m91/m120).

__global__ __launch_bounds__(512, 2) void gemm1_mfma_bias_relu(
        const unsigned short* __restrict__ A,    // [M][128] bf16
        const unsigned short* __restrict__ Bt,   // [256][128] bf16
        const float* __restrict__ bias,          // [256] fp32
        unsigned short* __restrict__ C, int M) {
    constexpr int K = FDIM, Nc = HDIM, LDT = 32;
    __shared__ unsigned short As[128 * LDT];     // 8KB
    __shared__ unsigned short Bs[256 * LDT];     // 16KB
    int tid = threadIdx.x;
    int lane = tid & 63, wave = tid >> 6;
    int wm = (wave >> 2) * 64, wn = (wave & 3) * 64;
    int bm = blockIdx.x * 128;
    int l15 = lane & 15, quad = lane >> 4;

    floatx4 zero = {0.f, 0.f, 0.f, 0.f};
    floatx4 acc[4][4];
    #pragma unroll
    for (int s = 0; s < 4; ++s)
        #pragma unroll
        for (int t = 0; t < 4; ++t) acc[s][t] = zero;

    for (int k0 = 0; k0 < K; k0 += 32) {
        {   // A: 512 chunks of 16B; chunk c = wave*64+lane; lds base wave-uniform
            int c = tid;
            gload16(&A[(size_t)(bm + (c >> 2)) * K + k0 + (c & 3) * 8], &As[wave * 512]);
        }
        {   // B: 1024 chunks; two per thread
            int c = tid;
            gload16(&Bt[(size_t)(c >> 2) * K + k0 + (c & 3) * 8], &Bs[wave * 512]);
            int c2 = tid + 512;
            gload16(&Bt[(size_t)(c2 >> 2) * K + k0 + (c2 & 3) * 8], &Bs[4096 + wave * 512]);
        }
        __syncthreads();
        short8 af[4], bf[4];
        #pragma unroll
        for (int s = 0; s < 4; ++s)
            af[s] = *(const short8*)&As[(wm + s * 16 + l15) * LDT + quad * 8];
        #pragma unroll
        for (int t = 0; t < 4; ++t)
            bf[t] = *(const short8*)&Bs[(wn + t * 16 + l15) * LDT + quad * 8];
        #pragma unroll
        for (int s = 0; s < 4; ++s)
            #pragma unroll
            for (int t = 0; t < 4; ++t)
                acc[s][t] = __builtin_amdgcn_mfma_f32_16x16x32_bf16(af[s], bf[t], acc[s][t], 0, 0, 0);
        __syncthreads();
    }
    #pragma unroll
    for (int s = 0; s < 4; ++s) {
        int row0 = bm + wm + s * 16 + quad * 4;
        #pragma unroll
        for (int t = 0; t < 4; ++t) {
            int col = wn + t * 16 + l15;
            float bb = bias[col];
            #pragma unroll
            for (int r = 0; r < 4; ++r) {
                int row = row0 + r;
                if (row < M)
                    C[(size_t)row * Nc + col] = f2bf(fmaxf(acc[s][t][r] + bb, 0.f));
            }
        }
    }
}

// GEMM2 fused with mean-pool numerator: relu(a1 @ W2 + b2) segment-summed by batch[] into
// pool[G][256] via fp32 atomics (batch sorted -> mostly 1 atomic per 4-row group).
__global__ __launch_bounds__(512, 2) void gemm2_pool(
        const unsigned short* __restrict__ A,    // [M][256] bf16 (a1b)
        const unsigned short* __restrict__ Bt,   // [256][256] bf16
        const float* __restrict__ bias,          // [256] fp32
        const int* __restrict__ batch,           // [M] sorted graph ids
        float* __restrict__ pool, int M) {       // [G][256] fp32, pre-zeroed
    constexpr int K = HDIM, Nc = HDIM, LDT = 32;
    __shared__ unsigned short As[128 * LDT];
    __shared__ unsigned short Bs[256 * LDT];
    int tid = threadIdx.x;
    int lane = tid & 63, wave = tid >> 6;
    int wm = (wave >> 2) * 64, wn = (wave & 3) * 64;
    int bm = blockIdx.x * 128;
    int l15 = lane & 15, quad = lane >> 4;

    floatx4 zero = {0.f, 0.f, 0.f, 0.f};
    floatx4 acc[4][4];
    #pragma unroll
    for (int s = 0; s < 4; ++s)
        #pragma unroll
        for (int t = 0; t < 4; ++t) acc[s][t] = zero;

    for (int k0 = 0; k0 < K; k0 += 32) {
        {
            int c = tid;
            gload16(&A[(size_t)(bm + (c >> 2)) * K + k0 + (c & 3) * 8], &As[wave * 512]);
        }
        {
            int c = tid;
            gload16(&Bt[(size_t)(c >> 2) * K + k0 + (c & 3) * 8], &Bs[wave * 512]);
            int c2 = tid + 512;
            gload16(&Bt[(size_t)(c2 >> 2) * K + k0 + (c2 & 3) * 8], &Bs[4096 + wave * 512]);
        }
        __syncthreads();
        short8 af[4], bf[4];
        #pragma unroll
        for (int s = 0; s < 4; ++s)
            af[s] = *(const short8*)&As[(wm + s * 16 + l15) * LDT + quad * 8];
        #pragma unroll
        for (int t = 0; t < 4; ++t)
            bf[t] = *(const short8*)&Bs[(wn + t * 16 + l15) * LDT + quad * 8];
        #pragma unroll
        for (int s = 0; s < 4; ++s)
            #pragma unroll
            for (int t = 0; t < 4; ++t)
                acc[s][t] = __builtin_amdgcn_mfma_f32_16x16x32_bf16(af[s], bf[t], acc[s][t], 0, 0, 0);
        __syncthreads();
    }
    // epilogue: segment-sum 4-row groups into pool
    #pragma unroll
    for (int s = 0; s < 4; ++s) {
        int row0 = bm + wm + s * 16 + quad * 4;
        if (row0 >= M) continue;
        bool full = (row0 + 3 < M);
        int gA = batch[row0];
        int gB = full ? batch[row0 + 3] : gA;
        bool same = full && (gA == gB);
        #pragma unroll
        for (int t = 0; t < 4; ++t) {
            int col = wn + t * 16 + l15;
            float bb = bias[col];
            if (same) {
                float v = fmaxf(acc[s][t][0] + bb, 0.f) + fmaxf(acc[s][t][1] + bb, 0.f)
                        + fmaxf(acc[s][t][2] + bb, 0.f) + fmaxf(acc[s][t][3] + bb, 0.f);
                atomicAdd(&pool[(size_t)gA * Nc + col], v);
            } else {
                #pragma unroll
                for (int r = 0; r < 4; ++r) {
                    int row = row0 + r;
                    if (row < M) {
                        float v = fmaxf(acc[s][t][r] + bb, 0.f);
                        atomicAdd(&pool[(size_t)batch[row] * Nc + col], v);
                    }
                }
            }
        }
    }
}

// ---------------- head: one block per graph, reads pooled sums ----------------

__device__ __forceinline__ int lower_bound_i(const int* __restrict__ a, int n, int v) {
    int lo = 0, hi = n;
    while (lo < hi) {
        int mid = (lo + hi) >> 1;
        if (a[mid] < v) lo = mid + 1; else hi = mid;
    }
    return lo;
}

__global__ __launch_bounds__(256) void head_kernel(const float* __restrict__ pool,
                                                   const int* __restrict__ batch,
                                                   const float* __restrict__ num_atoms,
                                                   const float* __restrict__ W3, const float* __restrict__ b3,
                                                   const float* __restrict__ W4, const float* __restrict__ b4,
                                                   float* __restrict__ out, int n) {
    int g = blockIdx.x;
    int tid = threadIdx.x;
    __shared__ int s_lo, s_hi;
    if (tid == 0) {
        s_lo = lower_bound_i(batch, n, g);
        s_hi = lower_bound_i(batch, n, g + 1);
    }
    __syncthreads();
    float cnt = (float)(s_hi - s_lo);

    __shared__ float zin[HDIM + 1];
    __shared__ float z[32];
    zin[tid] = pool[(size_t)g * HDIM + tid] / fmaxf(cnt, 1.0f);
    if (tid == 0) zin[HDIM] = num_atoms[g];
    __syncthreads();
    if (tid < 32) {
        float a = b3[tid];
        for (int k = 0; k < HDIM + 1; ++k) a = fmaf(zin[k], W3[k * 32 + tid], a);
        z[tid] = fmaxf(a, 0.f);
    }
    __syncthreads();
    if (tid < 4) {
        float a = b4[tid];
        #pragma unroll
        for (int k = 0; k < 32; ++k) a = fmaf(z[k], W4[k * 4 + tid], a);
        out[g * 4 + tid] = a;
    }
}

// ---------------- launch ----------------

extern "C" void kernel_launch(void* const* d_in, const int* in_sizes, int n_in,
                              void* d_out, int out_size, void* d_ws, size_t ws_size,
                              hipStream_t stream) {
    const float* x         = (const float*)d_in[0];
    const int*   edge_idx  = (const int*)d_in[1];
    const int*   batch     = (const int*)d_in[2];
    const float* num_atoms = (const float*)d_in[3];
    const float* W1 = (const float*)d_in[4];
    const float* b1 = (const float*)d_in[5];
    const float* W2 = (const float*)d_in[6];
    const float* b2 = (const float*)d_in[7];
    const float* W3 = (const float*)d_in[8];
    const float* b3 = (const float*)d_in[9];
    const float* W4 = (const float*)d_in[10];
    const float* b4 = (const float*)d_in[11];
    float* out = (float*)d_out;

    const int n = NN, e = EE;
    const int* e_src = edge_idx;
    const int* e_dst = edge_idx + e;

    // workspace (256B aligned). Lifetime aliasing:
    //   P (25.6MB): {x_bf [N,128]bf16 ; a0b [N,128]bf16} live through gemm1,
    //               then whole P reused as a1b [N,256]bf16 (agg256 out).
    //   Q (25.6MB): h1b [N,256]bf16 (gemm1 out, dead after agg256). Also absorbs GEMM
    //               staging over-reads past row M.
    //   pool (512KB): [G,256] fp32 pooled sums (gemm2_pool out -> head).
    char* ws = (char*)d_ws;
    size_t off = 0;
    auto carve = [&](size_t bytes) -> void* {
        void* p = ws + off;
        off = (off + bytes + 255) & ~(size_t)255;
        return p;
    };
    int*   deg_i    = (int*)carve((size_t)n * 4);
    int*   row_off  = (int*)carve((size_t)(n + 1) * 4);
    int*   blk_sums = (int*)carve((size_t)256 * 4);
    float* dinv     = (float*)carve((size_t)n * 4);
    int*   epos     = (int*)carve((size_t)e * 4);
    unsigned short* W1t = (unsigned short*)carve((size_t)FDIM * HDIM * 2);
    unsigned short* W2t = (unsigned short*)carve((size_t)HDIM * HDIM * 2);
    int2*  csr      = (int2*)carve((size_t)e * 8);
    unsigned short* P = (unsigned short*)carve((size_t)n * HDIM * 2);
    unsigned short* Q = (unsigned short*)carve((size_t)n * HDIM * 2);
    float* pool     = (float*)carve((size_t)GG * HDIM * 4);
    unsigned short* x_bf = P;                       // [N,128] bf16
    unsigned short* a0b  = P + (size_t)n * FDIM;    // [N,128] bf16
    unsigned short* a1b  = P;                       // [N,256] bf16 (x_bf/a0b dead)
    unsigned short* h1b  = Q;                       // [N,256] bf16
    (void)ws_size; (void)n_in; (void)in_sizes; (void)out_size;

    // cast x + transpose-cast W1,W2 + zero deg/pool, one dispatch (must precede hist)
    cast_all<<<(CAST_TOTAL + 255) / 256, 256, 0, stream>>>(
        x, x_bf, W1, W1t, W2, W2t, deg_i, pool);
    hist_kernel<<<1024, 256, 0, stream>>>(e_dst, deg_i, epos, e);
    scan_part<<<SCAN_NB, 256, 0, stream>>>(deg_i, row_off, blk_sums, dinv, n);
    scan_sums<<<1, 256, 0, stream>>>(blk_sums, SCAN_NB);
    scan_add<<<SCAN_NB, 256, 0, stream>>>(row_off, blk_sums, n, e);
    scatter_kernel<<<1024, 256, 0, stream>>>(e_src, e_dst, row_off, epos, dinv, csr, e);

    int gemm_grid = (n + 127) / 128;
    // L1: a0 = agg(x_bf) bf16; h1b = relu(a0 @ W1 + b1) bf16
    gcn_agg128_bf16<<<(n + 3) / 4, 256, 0, stream>>>(x_bf, row_off, csr, dinv, a0b, n);
    gemm1_mfma_bias_relu<<<gemm_grid, 512, 0, stream>>>(a0b, W1t, b1, h1b, n);
    // L2: a1 = agg(h1b) bf16; pool += segsum(relu(a1 @ W2 + b2))
    gcn_agg256_bf16<<<(n + 3) / 4, 256, 0, stream>>>(h1b, row_off, csr, dinv, a1b, n);
    gemm2_pool<<<gemm_grid, 512, 0, stream>>>(a1b, W2t, b2, batch, pool, n);
    // head
    head_kernel<<<GG, 256, 0, stream>>>(pool, batch, num_atoms, W3, b3, W4, b4, out, n);
}

// Round 10
// 296.966 us; speedup vs baseline: 1.2829x; 1.0850x over previous
//
#include <hip/hip_runtime.h>
#include <hip/hip_bf16.h>
#include <hip/hip_fp8.h>

// GNN: 2-layer GCN (N=50000, E=800000, F=128, H=256) + mean-pool (G=512) + MLP head (257->32->4)
// Key identity: segment_sum((xW)[src]*norm) == (segment_sum(x[src]*norm)) @ W  (GCN agg is linear)
//   prep:  cast_all (x->bf16, W transpose, zero deg/pool) -> hist(+epos) -> scan -> scatter
//   L1: agg128 -> a0; h1 = relu(a0 @ W1 + b1) -> FP8 e4m3   [MFMA, 128x256 tile]
//   L2: agg256_fp8(h1) -> a1 bf16; gemm2_pool: relu(a1 @ W2 + b2) pooled into pool[G,256]
//   head: per-graph block: mean + 257->32->4 MLP
// R8/R9: widened gathers NEUTRAL -> agg at 8-XCD compulsory BYTES floor (FETCH = 8 x table).
// R11/R13: sliced agg abandoned (L2-affinity real but 8x wave-count overhead).
// R15: agg+GEMM fusion REFUTED (block barrier cut gather TLP 8x). R16: atomic-free scatter
//   + merged zeroing (348->322).
// R17: bytes floor attacked directly: h1 table stored fp8 e4m3 (25.6->12.8MB), agg256
//   restructured to 16 lanes/row x 16B (agg128 control flow), HW cvt_pk_f32_fp8 decode.
//   x stays bf16 (isolate error source). Predicted agg256 58.7 -> ~35us.

#define NN 50000
#define EE 800000
#define FDIM 128
#define HDIM 256
#define GG 512
#define SCAN_NB ((NN + 255) / 256)

typedef __attribute__((ext_vector_type(8))) short short8;     // 8 bf16 = 4 VGPRs (MFMA A/B frag)
typedef __attribute__((ext_vector_type(4))) float floatx4;    // MFMA C/D frag
typedef __attribute__((ext_vector_type(2))) float floatx2;

__device__ __forceinline__ unsigned short f2bf(float f) {   // RNE
    unsigned u = __float_as_uint(f);
    return (unsigned short)((u + 0x7FFF + ((u >> 16) & 1)) >> 16);
}
__device__ __forceinline__ float bflo(unsigned v) { return __uint_as_float(v << 16); }
__device__ __forceinline__ float bfhi(unsigned v) { return __uint_as_float(v & 0xFFFF0000u); }

// fp8 e4m3 (OCP on gfx950) encode/decode via HW cvt; fallback to hip_fp8 type.
__device__ __forceinline__ unsigned char enc8(float v) {
#if defined(__has_builtin) && __has_builtin(__builtin_amdgcn_cvt_pk_fp8_f32)
    return (unsigned char)(__builtin_amdgcn_cvt_pk_fp8_f32(v, v, 0, false) & 0xFF);
#else
    __hip_fp8_e4m3 q(v);
    return (unsigned char)q.__x;
#endif
}
__device__ __forceinline__ void dec4(int d, float* f) {   // 4 fp8 bytes -> 4 floats
#if defined(__has_builtin) && __has_builtin(__builtin_amdgcn_cvt_pk_f32_fp8)
    floatx2 lo = __builtin_amdgcn_cvt_pk_f32_fp8(d, false);
    floatx2 hi = __builtin_amdgcn_cvt_pk_f32_fp8(d, true);
    f[0] = lo.x; f[1] = lo.y; f[2] = hi.x; f[3] = hi.y;
#else
    unsigned u = (unsigned)d;
    #pragma unroll
    for (int i = 0; i < 4; ++i) {
        __hip_fp8_e4m3 t; t.__x = (__hip_fp8_storage_t)((u >> (8 * i)) & 0xFF);
        f[i] = (float)t;
    }
#endif
}

// async global->LDS, 16B per lane. lds ptr must be wave-uniform (HW adds lane*16).
__device__ __forceinline__ void gload16(const void* g, void* l) {
    __builtin_amdgcn_global_load_lds((const __attribute__((address_space(1))) void*)g,
                                     (__attribute__((address_space(3))) void*)l, 16, 0, 0);
}

// ---------------- prep kernels ----------------

// hist + per-edge ordinal: epos[i] = old count of dst[i]. Scatter then needs no atomics.
__global__ void hist_kernel(const int* __restrict__ dst, int* __restrict__ deg,
                            int* __restrict__ epos, int e) {
    int i = blockIdx.x * blockDim.x + threadIdx.x;
    int stride = gridDim.x * blockDim.x;
    for (; i < e; i += stride) epos[i] = atomicAdd(&deg[dst[i]], 1);
}

__global__ __launch_bounds__(256) void scan_part(const int* __restrict__ deg,
                                                 int* __restrict__ row_off,
                                                 int* __restrict__ blk_sums,
                                                 float* __restrict__ dinv, int n) {
    __shared__ int s[256];
    int tid = threadIdx.x;
    int i = blockIdx.x * 256 + tid;
    int v = (i < n) ? deg[i] : 0;
    if (i < n) dinv[i] = rsqrtf((float)v + 1.0f);
    s[tid] = v;
    __syncthreads();
    #pragma unroll
    for (int off = 1; off < 256; off <<= 1) {
        int t = (tid >= off) ? s[tid - off] : 0;
        __syncthreads();
        s[tid] += t;
        __syncthreads();
    }
    if (i < n) row_off[i] = s[tid] - v;
    if (tid == 255) blk_sums[blockIdx.x] = s[255];
}

__global__ __launch_bounds__(256) void scan_sums(int* __restrict__ blk_sums, int nb) {
    __shared__ int s[256];
    int tid = threadIdx.x;
    int v = (tid < nb) ? blk_sums[tid] : 0;
    s[tid] = v;
    __syncthreads();
    #pragma unroll
    for (int off = 1; off < 256; off <<= 1) {
        int t = (tid >= off) ? s[tid - off] : 0;
        __syncthreads();
        s[tid] += t;
        __syncthreads();
    }
    if (tid < nb) blk_sums[tid] = s[tid] - v;
}

__global__ __launch_bounds__(256) void scan_add(int* __restrict__ row_off,
                                                const int* __restrict__ blk_sums,
                                                int n, int e) {
    int i = blockIdx.x * 256 + threadIdx.x;
    if (i < n) row_off[i] += blk_sums[blockIdx.x];
    if (i == 0) row_off[n] = e;
}

// atomic-free scatter: position = row_off[dst] + epos (ordinal captured in hist)
__global__ void scatter_kernel(const int* __restrict__ src, const int* __restrict__ dst,
                               const int* __restrict__ row_off, const int* __restrict__ epos,
                               const float* __restrict__ dinv,
                               int2* __restrict__ csr, int e) {
    int i = blockIdx.x * blockDim.x + threadIdx.x;
    int stride = gridDim.x * blockDim.x;
    for (; i < e; i += stride) {
        int s = src[i], d = dst[i];
        int pos = row_off[d] + epos[i];
        csr[pos] = make_int2(s, __float_as_int(dinv[s] * dinv[d]));
    }
}

// merged: x fp32->bf16 cast + W1/W2 transpose-cast + zero deg/pool. One dispatch.
#define XCHUNKS (NN * FDIM / 4)            // 1,600,000 float4 groups
#define CAST_TOTAL (XCHUNKS + FDIM * HDIM + HDIM * HDIM + NN / 4 + GG * HDIM / 4)
__global__ __launch_bounds__(256) void cast_all(const float* __restrict__ x,
                                                unsigned short* __restrict__ x_bf,
                                                const float* __restrict__ W1,
                                                unsigned short* __restrict__ W1t,
                                                const float* __restrict__ W2,
                                                unsigned short* __restrict__ W2t,
                                                int* __restrict__ deg,
                                                float* __restrict__ pool) {
    int idx = blockIdx.x * 256 + threadIdx.x;
    if (idx < XCHUNKS) {
        int i = idx * 4;
        float4 v = *(const float4*)&x[i];
        ushort4 o;
        o.x = f2bf(v.x); o.y = f2bf(v.y); o.z = f2bf(v.z); o.w = f2bf(v.w);
        *(ushort4*)&x_bf[i] = o;
        return;
    }
    int r = idx - XCHUNKS;
    if (r < FDIM * HDIM) {               // W1t[n][k] = bf16(W1[k][n]), K=128, Nc=256
        int nn = r / FDIM, k = r - nn * FDIM;
        W1t[r] = f2bf(W1[(size_t)k * HDIM + nn]);
        return;
    }
    r -= FDIM * HDIM;
    if (r < HDIM * HDIM) {               // W2t[n][k] = bf16(W2[k][n]), K=256, Nc=256
        int nn = r / HDIM, k = r - nn * HDIM;
        W2t[r] = f2bf(W2[(size_t)k * HDIM + nn]);
        return;
    }
    r -= HDIM * HDIM;
    if (r < NN / 4) {                    // zero deg (50000 % 4 == 0)
        int4 z = {0, 0, 0, 0};
        *(int4*)&deg[r * 4] = z;
        return;
    }
    r -= NN / 4;
    if (r < GG * HDIM / 4) {             // zero pool
        float4 z = {0.f, 0.f, 0.f, 0.f};
        *(float4*)&pool[r * 4] = z;
    }
}

// ---------------- GCN aggregation ----------------
// out[d] = sum_e in[src_e]*w_e + in[d]*dinv[d]^2
// wave-per-node, dwordx4 gathers (16B/lane). Wave split across edges.
// At the 8-XCD compulsory-traffic floor (FETCH = 8 x table bytes) -> R17 shrinks the bytes.
// NOTE: macro param must NOT be named 'w' (collides with .w member access).

#define FMA8(v, wgt) do { unsigned _u; \
    _u = (unsigned)(v).x; acc0 = fmaf(bflo(_u), (wgt), acc0); acc1 = fmaf(bfhi(_u), (wgt), acc1); \
    _u = (unsigned)(v).y; acc2 = fmaf(bflo(_u), (wgt), acc2); acc3 = fmaf(bfhi(_u), (wgt), acc3); \
    _u = (unsigned)(v).z; acc4 = fmaf(bflo(_u), (wgt), acc4); acc5 = fmaf(bfhi(_u), (wgt), acc5); \
    _u = (unsigned)(v).w; acc6 = fmaf(bflo(_u), (wgt), acc6); acc7 = fmaf(bfhi(_u), (wgt), acc7); } while (0)

__device__ __forceinline__ void fma16(const int4& g, float wgt, float* acc) {
    float f[16];
    dec4(g.x, f); dec4(g.y, f + 4); dec4(g.z, f + 8); dec4(g.w, f + 12);
    #pragma unroll
    for (int i = 0; i < 16; ++i) acc[i] = fmaf(f[i], wgt, acc[i]);
}

// L2 aggregation over the fp8 h1 table: row = 256 fp8 = 256B; 16 lanes x 16B per row;
// sub = lane>>4 -> 4 edge slots; 2 int4 gathers (8 edges) in flight (agg128 control flow).
// Output a1 in bf16 [N][256].
__global__ __launch_bounds__(256) void gcn_agg256_fp8(const unsigned char* __restrict__ in,
                                                      const int* __restrict__ row_off,
                                                      const int2* __restrict__ csr,
                                                      const float* __restrict__ dinv,
                                                      unsigned short* __restrict__ out, int n) {
    int wave = threadIdx.x >> 6;
    int lane = threadIdx.x & 63;
    int node = blockIdx.x * 4 + wave;
    if (node >= n) return;
    int sub = lane >> 4;          // edge slot 0..3
    int fl  = lane & 15;          // 16B chunk within 256B row
    float di = dinv[node];
    float w0 = (sub == 0) ? di * di : 0.f;

    float acc[16];
    {   // self term
        int4 sv = *(const int4*)&in[(size_t)node * 256 + fl * 16];
        float f[16];
        dec4(sv.x, f); dec4(sv.y, f + 4); dec4(sv.z, f + 8); dec4(sv.w, f + 12);
        #pragma unroll
        for (int i = 0; i < 16; ++i) acc[i] = f[i] * w0;
    }

    int beg = __builtin_amdgcn_readfirstlane(row_off[node]);
    int end = __builtin_amdgcn_readfirstlane(row_off[node + 1]);
    int cnt = end - beg;
    if (cnt > 0) {
        int nIter = (cnt + 7) >> 3;                    // 8 edges / iter (2 gathers)
        int base = beg;
        int last = end - 1;
        int i0 = base + sub, i1 = base + 4 + sub;
        int2 c0 = csr[i0 < end ? i0 : last];
        int2 c1 = csr[i1 < end ? i1 : last];
        for (int it = 0; it < nIter; ++it) {
            int4 g0 = *(const int4*)&in[(size_t)c0.x * 256 + fl * 16];
            int4 g1 = *(const int4*)&in[(size_t)c1.x * 256 + fl * 16];
            float we0 = (base + sub < end) ? __int_as_float(c0.y) : 0.f;
            float we1 = (base + 4 + sub < end) ? __int_as_float(c1.y) : 0.f;
            int nb = base + 8;
            int j0 = nb + sub, j1 = nb + 4 + sub;
            int2 n0 = csr[j0 < end ? j0 : last];
            int2 n1 = csr[j1 < end ? j1 : last];
            fma16(g0, we0, acc); fma16(g1, we1, acc);
            c0 = n0; c1 = n1; base = nb;
        }
    }
    // combine 4 edge-slots (lanes sharing fl differ in bits 4..5)
    #pragma unroll
    for (int i = 0; i < 16; ++i) {
        acc[i] += __shfl_xor(acc[i], 16);
        acc[i] += __shfl_xor(acc[i], 32);
    }
    if (sub == 0) {
        int4 o0, o1;
        o0.x = (int)((unsigned)f2bf(acc[0])  | ((unsigned)f2bf(acc[1])  << 16));
        o0.y = (int)((unsigned)f2bf(acc[2])  | ((unsigned)f2bf(acc[3])  << 16));
        o0.z = (int)((unsigned)f2bf(acc[4])  | ((unsigned)f2bf(acc[5])  << 16));
        o0.w = (int)((unsigned)f2bf(acc[6])  | ((unsigned)f2bf(acc[7])  << 16));
        o1.x = (int)((unsigned)f2bf(acc[8])  | ((unsigned)f2bf(acc[9])  << 16));
        o1.y = (int)((unsigned)f2bf(acc[10]) | ((unsigned)f2bf(acc[11]) << 16));
        o1.z = (int)((unsigned)f2bf(acc[12]) | ((unsigned)f2bf(acc[13]) << 16));
        o1.w = (int)((unsigned)f2bf(acc[14]) | ((unsigned)f2bf(acc[15]) << 16));
        *(int4*)&out[(size_t)node * 256 + fl * 16] = o0;
        *(int4*)&out[(size_t)node * 256 + fl * 16 + 8] = o1;
    }
}

__global__ __launch_bounds__(256) void gcn_agg128_bf16(const unsigned short* __restrict__ in,
                                                       const int* __restrict__ row_off,
                                                       const int2* __restrict__ csr,
                                                       const float* __restrict__ dinv,
                                                       unsigned short* __restrict__ out, int n) {
    int wave = threadIdx.x >> 6;
    int lane = threadIdx.x & 63;
    int node = blockIdx.x * 4 + wave;
    if (node >= n) return;
    int sub = lane >> 4;          // edge slot 0..3
    int fl  = lane & 15;          // 16B feature chunk within row
    float di = dinv[node];
    float w0 = (sub == 0) ? di * di : 0.f;

    float acc0, acc1, acc2, acc3, acc4, acc5, acc6, acc7;
    {   // self term
        int4 sv = *(const int4*)&in[(size_t)node * 128 + fl * 8];
        unsigned _u;
        _u = (unsigned)sv.x; acc0 = bflo(_u) * w0; acc1 = bfhi(_u) * w0;
        _u = (unsigned)sv.y; acc2 = bflo(_u) * w0; acc3 = bfhi(_u) * w0;
        _u = (unsigned)sv.z; acc4 = bflo(_u) * w0; acc5 = bfhi(_u) * w0;
        _u = (unsigned)sv.w; acc6 = bflo(_u) * w0; acc7 = bfhi(_u) * w0;
    }

    int beg = __builtin_amdgcn_readfirstlane(row_off[node]);
    int end = __builtin_amdgcn_readfirstlane(row_off[node + 1]);
    int cnt = end - beg;
    if (cnt > 0) {
        int nIter = (cnt + 7) >> 3;                    // 8 edges / iter (2 gathers)
        int base = beg;
        int last = end - 1;
        int i0 = base + sub, i1 = base + 4 + sub;
        int2 c0 = csr[i0 < end ? i0 : last];
        int2 c1 = csr[i1 < end ? i1 : last];
        for (int it = 0; it < nIter; ++it) {
            int4 g0 = *(const int4*)&in[(size_t)c0.x * 128 + fl * 8];
            int4 g1 = *(const int4*)&in[(size_t)c1.x * 128 + fl * 8];
            float we0 = (base + sub < end) ? __int_as_float(c0.y) : 0.f;
            float we1 = (base + 4 + sub < end) ? __int_as_float(c1.y) : 0.f;
            int nb = base + 8;
            int j0 = nb + sub, j1 = nb + 4 + sub;
            int2 n0 = csr[j0 < end ? j0 : last];
            int2 n1 = csr[j1 < end ? j1 : last];
            FMA8(g0, we0); FMA8(g1, we1);
            c0 = n0; c1 = n1; base = nb;
        }
    }
    // combine 4 edge-slots
    acc0 += __shfl_xor(acc0, 16); acc1 += __shfl_xor(acc1, 16);
    acc2 += __shfl_xor(acc2, 16); acc3 += __shfl_xor(acc3, 16);
    acc4 += __shfl_xor(acc4, 16); acc5 += __shfl_xor(acc5, 16);
    acc6 += __shfl_xor(acc6, 16); acc7 += __shfl_xor(acc7, 16);
    acc0 += __shfl_xor(acc0, 32); acc1 += __shfl_xor(acc1, 32);
    acc2 += __shfl_xor(acc2, 32); acc3 += __shfl_xor(acc3, 32);
    acc4 += __shfl_xor(acc4, 32); acc5 += __shfl_xor(acc5, 32);
    acc6 += __shfl_xor(acc6, 32); acc7 += __shfl_xor(acc7, 32);
    if (sub == 0) {
        int4 o;
        o.x = (int)((unsigned)f2bf(acc0) | ((unsigned)f2bf(acc1) << 16));
        o.y = (int)((unsigned)f2bf(acc2) | ((unsigned)f2bf(acc3) << 16));
        o.z = (int)((unsigned)f2bf(acc4) | ((unsigned)f2bf(acc5) << 16));
        o.w = (int)((unsigned)f2bf(acc6) | ((unsigned)f2bf(acc7) << 16));
        *(int4*)&out[(size_t)node * 128 + fl * 8] = o;
    }
}

// ---------------- bf16 MFMA GEMM, 128x256 single-column tile, 8 waves (2x4) ----------------
// A bf16 row-major [M][K], Bt bf16 [256][K] pre-transposed. Wave = 64x64 via 4x4 16x16x32.
// Staging via global_load_lds width=16 into LINEAR LDS (LDT=32). No staging guards:
// over-reads past M stay inside workspace. Verified layouts (learn_hip m89/m91/m120).
// R17: output is FP8 e4m3 (h1 table for agg256_fp8).

__global__ __launch_bounds__(512, 2) void gemm1_mfma_bias_relu(
        const unsigned short* __restrict__ A,    // [M][128] bf16
        const unsigned short* __restrict__ Bt,   // [256][128] bf16
        const float* __restrict__ bias,          // [256] fp32
        unsigned char* __restrict__ C, int M) {  // [M][256] fp8 e4m3
    constexpr int K = FDIM, Nc = HDIM, LDT = 32;
    __shared__ unsigned short As[128 * LDT];     // 8KB
    __shared__ unsigned short Bs[256 * LDT];     // 16KB
    int tid = threadIdx.x;
    int lane = tid & 63, wave = tid >> 6;
    int wm = (wave >> 2) * 64, wn = (wave & 3) * 64;
    int bm = blockIdx.x * 128;
    int l15 = lane & 15, quad = lane >> 4;

    floatx4 zero = {0.f, 0.f, 0.f, 0.f};
    floatx4 acc[4][4];
    #pragma unroll
    for (int s = 0; s < 4; ++s)
        #pragma unroll
        for (int t = 0; t < 4; ++t) acc[s][t] = zero;

    for (int k0 = 0; k0 < K; k0 += 32) {
        {   // A: 512 chunks of 16B; chunk c = wave*64+lane; lds base wave-uniform
            int c = tid;
            gload16(&A[(size_t)(bm + (c >> 2)) * K + k0 + (c & 3) * 8], &As[wave * 512]);
        }
        {   // B: 1024 chunks; two per thread
            int c = tid;
            gload16(&Bt[(size_t)(c >> 2) * K + k0 + (c & 3) * 8], &Bs[wave * 512]);
            int c2 = tid + 512;
            gload16(&Bt[(size_t)(c2 >> 2) * K + k0 + (c2 & 3) * 8], &Bs[4096 + wave * 512]);
        }
        __syncthreads();
        short8 af[4], bf[4];
        #pragma unroll
        for (int s = 0; s < 4; ++s)
            af[s] = *(const short8*)&As[(wm + s * 16 + l15) * LDT + quad * 8];
        #pragma unroll
        for (int t = 0; t < 4; ++t)
            bf[t] = *(const short8*)&Bs[(wn + t * 16 + l15) * LDT + quad * 8];
        #pragma unroll
        for (int s = 0; s < 4; ++s)
            #pragma unroll
            for (int t = 0; t < 4; ++t)
                acc[s][t] = __builtin_amdgcn_mfma_f32_16x16x32_bf16(af[s], bf[t], acc[s][t], 0, 0, 0);
        __syncthreads();
    }
    #pragma unroll
    for (int s = 0; s < 4; ++s) {
        int row0 = bm + wm + s * 16 + quad * 4;
        #pragma unroll
        for (int t = 0; t < 4; ++t) {
            int col = wn + t * 16 + l15;
            float bb = bias[col];
            #pragma unroll
            for (int r = 0; r < 4; ++r) {
                int row = row0 + r;
                if (row < M)
                    C[(size_t)row * Nc + col] = enc8(fmaxf(acc[s][t][r] + bb, 0.f));
            }
        }
    }
}

// GEMM2 fused with mean-pool numerator: relu(a1 @ W2 + b2) segment-summed by batch[] into
// pool[G][256] via fp32 atomics (batch sorted -> mostly 1 atomic per 4-row group).
__global__ __launch_bounds__(512, 2) void gemm2_pool(
        const unsigned short* __restrict__ A,    // [M][256] bf16 (a1b)
        const unsigned short* __restrict__ Bt,   // [256][256] bf16
        const float* __restrict__ bias,          // [256] fp32
        const int* __restrict__ batch,           // [M] sorted graph ids
        float* __restrict__ pool, int M) {       // [G][256] fp32, pre-zeroed
    constexpr int K = HDIM, Nc = HDIM, LDT = 32;
    __shared__ unsigned short As[128 * LDT];
    __shared__ unsigned short Bs[256 * LDT];
    int tid = threadIdx.x;
    int lane = tid & 63, wave = tid >> 6;
    int wm = (wave >> 2) * 64, wn = (wave & 3) * 64;
    int bm = blockIdx.x * 128;
    int l15 = lane & 15, quad = lane >> 4;

    floatx4 zero = {0.f, 0.f, 0.f, 0.f};
    floatx4 acc[4][4];
    #pragma unroll
    for (int s = 0; s < 4; ++s)
        #pragma unroll
        for (int t = 0; t < 4; ++t) acc[s][t] = zero;

    for (int k0 = 0; k0 < K; k0 += 32) {
        {
            int c = tid;
            gload16(&A[(size_t)(bm + (c >> 2)) * K + k0 + (c & 3) * 8], &As[wave * 512]);
        }
        {
            int c = tid;
            gload16(&Bt[(size_t)(c >> 2) * K + k0 + (c & 3) * 8], &Bs[wave * 512]);
            int c2 = tid + 512;
            gload16(&Bt[(size_t)(c2 >> 2) * K + k0 + (c2 & 3) * 8], &Bs[4096 + wave * 512]);
        }
        __syncthreads();
        short8 af[4], bf[4];
        #pragma unroll
        for (int s = 0; s < 4; ++s)
            af[s] = *(const short8*)&As[(wm + s * 16 + l15) * LDT + quad * 8];
        #pragma unroll
        for (int t = 0; t < 4; ++t)
            bf[t] = *(const short8*)&Bs[(wn + t * 16 + l15) * LDT + quad * 8];
        #pragma unroll
        for (int s = 0; s < 4; ++s)
            #pragma unroll
            for (int t = 0; t < 4; ++t)
                acc[s][t] = __builtin_amdgcn_mfma_f32_16x16x32_bf16(af[s], bf[t], acc[s][t], 0, 0, 0);
        __syncthreads();
    }
    // epilogue: segment-sum 4-row groups into pool
    #pragma unroll
    for (int s = 0; s < 4; ++s) {
        int row0 = bm + wm + s * 16 + quad * 4;
        if (row0 >= M) continue;
        bool full = (row0 + 3 < M);
        int gA = batch[row0];
        int gB = full ? batch[row0 + 3] : gA;
        bool same = full && (gA == gB);
        #pragma unroll
        for (int t = 0; t < 4; ++t) {
            int col = wn + t * 16 + l15;
            float bb = bias[col];
            if (same) {
                float v = fmaxf(acc[s][t][0] + bb, 0.f) + fmaxf(acc[s][t][1] + bb, 0.f)
                        + fmaxf(acc[s][t][2] + bb, 0.f) + fmaxf(acc[s][t][3] + bb, 0.f);
                atomicAdd(&pool[(size_t)gA * Nc + col], v);
            } else {
                #pragma unroll
                for (int r = 0; r < 4; ++r) {
                    int row = row0 + r;
                    if (row < M) {
                        float v = fmaxf(acc[s][t][r] + bb, 0.f);
                        atomicAdd(&pool[(size_t)batch[row] * Nc + col], v);
                    }
                }
            }
        }
    }
}

// ---------------- head: one block per graph, reads pooled sums ----------------

__device__ __forceinline__ int lower_bound_i(const int* __restrict__ a, int n, int v) {
    int lo = 0, hi = n;
    while (lo < hi) {
        int mid = (lo + hi) >> 1;
        if (a[mid] < v) lo = mid + 1; else hi = mid;
    }
    return lo;
}

__global__ __launch_bounds__(256) void head_kernel(const float* __restrict__ pool,
                                                   const int* __restrict__ batch,
                                                   const float* __restrict__ num_atoms,
                                                   const float* __restrict__ W3, const float* __restrict__ b3,
                                                   const float* __restrict__ W4, const float* __restrict__ b4,
                                                   float* __restrict__ out, int n) {
    int g = blockIdx.x;
    int tid = threadIdx.x;
    __shared__ int s_lo, s_hi;
    if (tid == 0) {
        s_lo = lower_bound_i(batch, n, g);
        s_hi = lower_bound_i(batch, n, g + 1);
    }
    __syncthreads();
    float cnt = (float)(s_hi - s_lo);

    __shared__ float zin[HDIM + 1];
    __shared__ float z[32];
    zin[tid] = pool[(size_t)g * HDIM + tid] / fmaxf(cnt, 1.0f);
    if (tid == 0) zin[HDIM] = num_atoms[g];
    __syncthreads();
    if (tid < 32) {
        float a = b3[tid];
        for (int k = 0; k < HDIM + 1; ++k) a = fmaf(zin[k], W3[k * 32 + tid], a);
        z[tid] = fmaxf(a, 0.f);
    }
    __syncthreads();
    if (tid < 4) {
        float a = b4[tid];
        #pragma unroll
        for (int k = 0; k < 32; ++k) a = fmaf(z[k], W4[k * 4 + tid], a);
        out[g * 4 + tid] = a;
    }
}

// ---------------- launch ----------------

extern "C" void kernel_launch(void* const* d_in, const int* in_sizes, int n_in,
                              void* d_out, int out_size, void* d_ws, size_t ws_size,
                              hipStream_t stream) {
    const float* x         = (const float*)d_in[0];
    const int*   edge_idx  = (const int*)d_in[1];
    const int*   batch     = (const int*)d_in[2];
    const float* num_atoms = (const float*)d_in[3];
    const float* W1 = (const float*)d_in[4];
    const float* b1 = (const float*)d_in[5];
    const float* W2 = (const float*)d_in[6];
    const float* b2 = (const float*)d_in[7];
    const float* W3 = (const float*)d_in[8];
    const float* b3 = (const float*)d_in[9];
    const float* W4 = (const float*)d_in[10];
    const float* b4 = (const float*)d_in[11];
    float* out = (float*)d_out;

    const int n = NN, e = EE;
    const int* e_src = edge_idx;
    const int* e_dst = edge_idx + e;

    // workspace (256B aligned). Lifetime aliasing:
    //   P (25.6MB): {x_bf [N,128]bf16 ; a0b [N,128]bf16} live through gemm1,
    //               then whole P reused as a1b [N,256]bf16 (agg256 out).
    //   Q (12.8MB): h1f8 [N,256]fp8 (gemm1 out, dead after agg256). Also absorbs GEMM
    //               staging over-reads past row M.
    //   pool (512KB): [G,256] fp32 pooled sums (gemm2_pool out -> head).
    char* ws = (char*)d_ws;
    size_t off = 0;
    auto carve = [&](size_t bytes) -> void* {
        void* p = ws + off;
        off = (off + bytes + 255) & ~(size_t)255;
        return p;
    };
    int*   deg_i    = (int*)carve((size_t)n * 4);
    int*   row_off  = (int*)carve((size_t)(n + 1) * 4);
    int*   blk_sums = (int*)carve((size_t)256 * 4);
    float* dinv     = (float*)carve((size_t)n * 4);
    int*   epos     = (int*)carve((size_t)e * 4);
    unsigned short* W1t = (unsigned short*)carve((size_t)FDIM * HDIM * 2);
    unsigned short* W2t = (unsigned short*)carve((size_t)HDIM * HDIM * 2);
    int2*  csr      = (int2*)carve((size_t)e * 8);
    unsigned short* P = (unsigned short*)carve((size_t)n * HDIM * 2);
    unsigned char*  Q = (unsigned char*)carve((size_t)n * HDIM);
    float* pool     = (float*)carve((size_t)GG * HDIM * 4);
    unsigned short* x_bf = P;                       // [N,128] bf16
    unsigned short* a0b  = P + (size_t)n * FDIM;    // [N,128] bf16
    unsigned short* a1b  = P;                       // [N,256] bf16 (x_bf/a0b dead)
    unsigned char*  h1f8 = Q;                       // [N,256] fp8 e4m3
    (void)ws_size; (void)n_in; (void)in_sizes; (void)out_size;

    // cast x + transpose-cast W1,W2 + zero deg/pool, one dispatch (must precede hist)
    cast_all<<<(CAST_TOTAL + 255) / 256, 256, 0, stream>>>(
        x, x_bf, W1, W1t, W2, W2t, deg_i, pool);
    hist_kernel<<<1024, 256, 0, stream>>>(e_dst, deg_i, epos, e);
    scan_part<<<SCAN_NB, 256, 0, stream>>>(deg_i, row_off, blk_sums, dinv, n);
    scan_sums<<<1, 256, 0, stream>>>(blk_sums, SCAN_NB);
    scan_add<<<SCAN_NB, 256, 0, stream>>>(row_off, blk_sums, n, e);
    scatter_kernel<<<1024, 256, 0, stream>>>(e_src, e_dst, row_off, epos, dinv, csr, e);

    int gemm_grid = (n + 127) / 128;
    // L1: a0 = agg(x_bf) bf16; h1f8 = fp8(relu(a0 @ W1 + b1))
    gcn_agg128_bf16<<<(n + 3) / 4, 256, 0, stream>>>(x_bf, row_off, csr, dinv, a0b, n);
    gemm1_mfma_bias_relu<<<gemm_grid, 512, 0, stream>>>(a0b, W1t, b1, h1f8, n);
    // L2: a1 = agg(h1f8) bf16; pool += segsum(relu(a1 @ W2 + b2))
    gcn_agg256_fp8<<<(n + 3) / 4, 256, 0, stream>>>(h1f8, row_off, csr, dinv, a1b, n);
    gemm2_pool<<<gemm_grid, 512, 0, stream>>>(a1b, W2t, b2, batch, pool, n);
    // head
    head_kernel<<<GG, 256, 0, stream>>>(pool, batch, num_atoms, W3, b3, W4, b4, out, n);
}